// Round 1
// baseline (94.324 us; speedup 1.0000x reference)
//
#include <hip/hip_runtime.h>
#include <hip/hip_bf16.h>

typedef __bf16 bf16x8 __attribute__((ext_vector_type(8)));
typedef __bf16 bf16x4 __attribute__((ext_vector_type(4)));
typedef float f32x4 __attribute__((ext_vector_type(4)));

#define DMODEL 1024
#define NBATCH 4
#define NHEAD 16
#define NSEQ 1024
#define MROWS (NBATCH * NSEQ)   // 4096

// async global->LDS, 16B per lane. LDS dest must be wave-uniform base; HW adds lane*16.
__device__ __forceinline__ void gload_lds16(const void* g, void* l) {
  __builtin_amdgcn_global_load_lds(
      (const __attribute__((address_space(1))) unsigned int*)g,
      (__attribute__((address_space(3))) unsigned int*)l, 16, 0, 0);
}

// ---------------- fp32 -> bf16 conversion of x, Wv, Wo ----------------
__global__ void cvt_kernel(const float* __restrict__ x, const float* __restrict__ wv,
                           const float* __restrict__ wo, __hip_bfloat16* __restrict__ xb,
                           __hip_bfloat16* __restrict__ wvb, __hip_bfloat16* __restrict__ wob) {
  const int XQ = (MROWS * DMODEL) / 4;    // 1048576 float4s
  const int WQ = (DMODEL * DMODEL) / 4;   //  262144 float4s
  int t = blockIdx.x * 256 + threadIdx.x;
  const float* src;
  __hip_bfloat16* dst;
  int i;
  if (t < XQ) { src = x; dst = xb; i = t; }
  else if (t < XQ + WQ) { src = wv; dst = wvb; i = t - XQ; }
  else { src = wo; dst = wob; i = t - XQ - WQ; }
  float4 v = reinterpret_cast<const float4*>(src)[i];
  bf16x4 o = { (__bf16)v.x, (__bf16)v.y, (__bf16)v.z, (__bf16)v.w };
  reinterpret_cast<bf16x4*>(dst)[i] = o;
}

// ---------------- diag[b,h,n] = dot(fl,fr) over R=64; store exp(diag) ----------------
__global__ void diag_kernel(const float* __restrict__ fl, const float* __restrict__ fr,
                            float* __restrict__ ed) {
  int t = blockIdx.x * 256 + threadIdx.x;      // 16 threads per row
  int row = t >> 4, sub = t & 15;
  float4 a = reinterpret_cast<const float4*>(fl)[row * 16 + sub];
  float4 b = reinterpret_cast<const float4*>(fr)[row * 16 + sub];
  float s = a.x * b.x + a.y * b.y + a.z * b.z + a.w * b.w;
  s += __shfl_xor(s, 1);
  s += __shfl_xor(s, 2);
  s += __shfl_xor(s, 4);
  s += __shfl_xor(s, 8);
  if (sub == 0) ed[row] = expf(s);
}

// ---------------- per-batch column sums of value (bf16) into S (f32, atomics) ----------------
__global__ void colsum_kernel(const __hip_bfloat16* __restrict__ val, float* __restrict__ S) {
  // grid: (32 = 4 batches * 8 row-chunks, 4 = 1024/256), block 256
  int c = blockIdx.y * 256 + threadIdx.x;
  int b = blockIdx.x >> 3, ch = blockIdx.x & 7;
  const __hip_bfloat16* p = val + ((size_t)b * NSEQ + ch * 128) * DMODEL + c;
  float s = 0.f;
#pragma unroll 8
  for (int n = 0; n < 128; n++) s += __bfloat162float(p[(size_t)n * DMODEL]);
  atomicAdd(&S[b * DMODEL + c], s);
}

// ---------------- u = (S + (e-1)*v) / (e + N-1), bf16 out ----------------
__global__ void u_kernel(const __hip_bfloat16* __restrict__ val, const float* __restrict__ S,
                         const float* __restrict__ ed, __hip_bfloat16* __restrict__ u) {
  int t = blockIdx.x * 256 + threadIdx.x;   // one thread per 8 f's
  int r = t >> 7;            // row in [0,4096)
  int f = (t & 127) * 8;     // col, 8-aligned, stays in one head-block
  int b = r >> 10, n = r & 1023, h = f >> 6;
  float e = ed[(((b << 4) + h) << 10) + n];
  float inv = 1.0f / (e + (float)(NSEQ - 1));
  float em1 = e - 1.0f;
  bf16x8 v = *reinterpret_cast<const bf16x8*>(&val[(size_t)r * DMODEL + f]);
  f32x4 s0 = *reinterpret_cast<const f32x4*>(&S[b * DMODEL + f]);
  f32x4 s1 = *reinterpret_cast<const f32x4*>(&S[b * DMODEL + f + 4]);
  bf16x8 o;
#pragma unroll
  for (int j = 0; j < 4; j++) o[j] = (__bf16)((s0[j] + em1 * (float)v[j]) * inv);
#pragma unroll
  for (int j = 0; j < 4; j++) o[j + 4] = (__bf16)((s1[j] + em1 * (float)v[j + 4]) * inv);
  *reinterpret_cast<bf16x8*>(&u[(size_t)r * DMODEL + f]) = o;
}

// ---------------- C[m,n] = sum_k A[m,k] * B[n,k]  (both row-major, k contiguous) ----------------
__device__ __forceinline__ void store_val(float* p, float v) { *p = v; }
__device__ __forceinline__ void store_val(__hip_bfloat16* p, float v) { *p = __float2bfloat16(v); }

template <typename OutT>
__global__ __launch_bounds__(256) void gemm_bt(const __hip_bfloat16* __restrict__ A,
                                               const __hip_bfloat16* __restrict__ B,
                                               OutT* __restrict__ C, int M, int N, int K) {
  __shared__ __hip_bfloat16 As[128 * 32];
  __shared__ __hip_bfloat16 Bs[128 * 32];
  const int t = threadIdx.x;
  const int lane = t & 63;
  const int w = t >> 6;            // wave 0..3
  const int wm = w >> 1, wn = w & 1;
  const int tileM = blockIdx.y * 128, tileN = blockIdx.x * 128;

  const int fr = lane & 15;        // fragment row
  const int kg = lane >> 4;        // k-group (8 bf16 each)

  f32x4 acc[4][4] = {};

  // staging: thread t covers row t>>2 (and +64), bf16 col (t&3)*8
  const int srow = t >> 2;
  const int scol = (t & 3) * 8;
  const __hip_bfloat16* gA = A + (size_t)(tileM + srow) * K + scol;
  const __hip_bfloat16* gB = B + (size_t)(tileN + srow) * K + scol;

  for (int kb = 0; kb < K; kb += 32) {
    gload_lds16(gA + kb, &As[w * 512]);
    gload_lds16(gA + kb + (size_t)64 * K, &As[2048 + w * 512]);
    gload_lds16(gB + kb, &Bs[w * 512]);
    gload_lds16(gB + kb + (size_t)64 * K, &Bs[2048 + w * 512]);
    __syncthreads();   // drains vmcnt before barrier

    bf16x8 aF[4], bF[4];
#pragma unroll
    for (int i = 0; i < 4; i++) {
      aF[i] = *reinterpret_cast<const bf16x8*>(&As[(wm * 64 + i * 16 + fr) * 32 + kg * 8]);
      bF[i] = *reinterpret_cast<const bf16x8*>(&Bs[(wn * 64 + i * 16 + fr) * 32 + kg * 8]);
    }
#pragma unroll
    for (int i = 0; i < 4; i++)
#pragma unroll
      for (int j = 0; j < 4; j++)
        acc[i][j] = __builtin_amdgcn_mfma_f32_16x16x32_bf16(aF[i], bF[j], acc[i][j], 0, 0, 0);
    __syncthreads();
  }

  const int cr = (lane >> 4) * 4;  // C row base within fragment
  const int cc = lane & 15;        // C col within fragment
#pragma unroll
  for (int i = 0; i < 4; i++)
#pragma unroll
    for (int j = 0; j < 4; j++)
#pragma unroll
      for (int r = 0; r < 4; r++) {
        int row = tileM + wm * 64 + i * 16 + cr + r;
        int col = tileN + wn * 64 + j * 16 + cc;
        store_val(&C[(size_t)row * N + col], acc[i][j][r]);
      }
}

extern "C" void kernel_launch(void* const* d_in, const int* in_sizes, int n_in,
                              void* d_out, int out_size, void* d_ws, size_t ws_size,
                              hipStream_t stream) {
  const float* x  = (const float*)d_in[0];
  const float* fl = (const float*)d_in[1];
  const float* fr = (const float*)d_in[2];
  const float* Wv = (const float*)d_in[3];
  const float* Wo = (const float*)d_in[4];
  float* out = (float*)d_out;

  char* ws = (char*)d_ws;
  __hip_bfloat16* xb   = (__hip_bfloat16*)(ws);                          // 8 MB (reused as ub)
  __hip_bfloat16* wvb  = (__hip_bfloat16*)(ws + ( 8u << 20));            // 2 MB
  __hip_bfloat16* wob  = (__hip_bfloat16*)(ws + (10u << 20));            // 2 MB
  __hip_bfloat16* valb = (__hip_bfloat16*)(ws + (12u << 20));            // 8 MB
  float* S  = (float*)(ws + (20u << 20));                                // 16 KB
  float* ed = (float*)(ws + (20u << 20) + (64u << 10));                  // 256 KB
  __hip_bfloat16* ub = xb;  // xb is dead after GEMM1; reuse for u

  hipMemsetAsync(S, 0, NBATCH * DMODEL * sizeof(float), stream);
  cvt_kernel<<<6144, 256, 0, stream>>>(x, Wv, Wo, xb, wvb, wob);
  diag_kernel<<<4096, 256, 0, stream>>>(fl, fr, ed);
  gemm_bt<__hip_bfloat16><<<dim3(DMODEL / 128, MROWS / 128), 256, 0, stream>>>(
      xb, wvb, valb, MROWS, DMODEL, DMODEL);
  colsum_kernel<<<dim3(32, 4), 256, 0, stream>>>(valb, S);
  u_kernel<<<2048, 256, 0, stream>>>(valb, S, ed, ub);
  gemm_bt<float><<<dim3(DMODEL / 128, MROWS / 128), 256, 0, stream>>>(
      ub, wob, out, MROWS, DMODEL, DMODEL);
}

// Round 2
// 70.991 us; speedup vs baseline: 1.3287x; 1.3287x over previous
//
#include <hip/hip_runtime.h>
#include <hip/hip_bf16.h>

typedef __bf16 bf16x8 __attribute__((ext_vector_type(8)));
typedef __bf16 bf16x4 __attribute__((ext_vector_type(4)));
typedef float f32x4 __attribute__((ext_vector_type(4)));

#define DMODEL 1024
#define NBATCH 4
#define NHEAD 16
#define NSEQ 1024
#define MROWS (NBATCH * NSEQ)   // 4096

// async global->LDS, 16B per lane. LDS dest must be wave-uniform base; HW adds lane*16.
__device__ __forceinline__ void gload_lds16(const void* g, void* l) {
  __builtin_amdgcn_global_load_lds(
      (const __attribute__((address_space(1))) unsigned int*)g,
      (__attribute__((address_space(3))) unsigned int*)l, 16, 0, 0);
}

// ---------------- fp32 -> bf16 conversion of x, Wv, Wo ----------------
__global__ void cvt_kernel(const float* __restrict__ x, const float* __restrict__ wv,
                           const float* __restrict__ wo, __hip_bfloat16* __restrict__ xb,
                           __hip_bfloat16* __restrict__ wvb, __hip_bfloat16* __restrict__ wob) {
  const int XQ = (MROWS * DMODEL) / 4;    // 1048576 float4s
  const int WQ = (DMODEL * DMODEL) / 4;   //  262144 float4s
  int t = blockIdx.x * 256 + threadIdx.x;
  const float* src;
  __hip_bfloat16* dst;
  int i;
  if (t < XQ) { src = x; dst = xb; i = t; }
  else if (t < XQ + WQ) { src = wv; dst = wvb; i = t - XQ; }
  else { src = wo; dst = wob; i = t - XQ - WQ; }
  float4 v = reinterpret_cast<const float4*>(src)[i];
  bf16x4 o = { (__bf16)v.x, (__bf16)v.y, (__bf16)v.z, (__bf16)v.w };
  reinterpret_cast<bf16x4*>(dst)[i] = o;
}

// ---------------- diag[b,h,n] = dot(fl,fr) over R=64; store exp(diag). Also zeros S. ----------------
__global__ void diag_kernel(const float* __restrict__ fl, const float* __restrict__ fr,
                            float* __restrict__ ed, float* __restrict__ S) {
  if (blockIdx.x == 0) {
#pragma unroll
    for (int i = 0; i < (NBATCH * DMODEL) / 256; i++) S[i * 256 + threadIdx.x] = 0.f;
  }
  int t = blockIdx.x * 256 + threadIdx.x;      // 16 threads per row
  int row = t >> 4, sub = t & 15;
  float4 a = reinterpret_cast<const float4*>(fl)[row * 16 + sub];
  float4 b = reinterpret_cast<const float4*>(fr)[row * 16 + sub];
  float s = a.x * b.x + a.y * b.y + a.z * b.z + a.w * b.w;
  s += __shfl_xor(s, 1);
  s += __shfl_xor(s, 2);
  s += __shfl_xor(s, 4);
  s += __shfl_xor(s, 8);
  if (sub == 0) ed[row] = expf(s);
}

// ---------------- per-batch column sums of value (bf16) into S (f32, atomics) ----------------
__global__ void colsum_kernel(const __hip_bfloat16* __restrict__ val, float* __restrict__ S) {
  // grid: (32 = 4 batches * 8 row-chunks, 4 = 1024/256), block 256
  int c = blockIdx.y * 256 + threadIdx.x;
  int b = blockIdx.x >> 3, ch = blockIdx.x & 7;
  const __hip_bfloat16* p = val + ((size_t)b * NSEQ + ch * 128) * DMODEL + c;
  float s = 0.f;
#pragma unroll 8
  for (int n = 0; n < 128; n++) s += __bfloat162float(p[(size_t)n * DMODEL]);
  atomicAdd(&S[b * DMODEL + c], s);
}

// ---------------- u = (S + (e-1)*v) / (e + N-1), bf16 out ----------------
__global__ void u_kernel(const __hip_bfloat16* __restrict__ val, const float* __restrict__ S,
                         const float* __restrict__ ed, __hip_bfloat16* __restrict__ u) {
  int t = blockIdx.x * 256 + threadIdx.x;   // one thread per 8 f's
  int r = t >> 7;            // row in [0,4096)
  int f = (t & 127) * 8;     // col, 8-aligned, stays in one head-block
  int b = r >> 10, n = r & 1023, h = f >> 6;
  float e = ed[(((b << 4) + h) << 10) + n];
  float inv = 1.0f / (e + (float)(NSEQ - 1));
  float em1 = e - 1.0f;
  bf16x8 v = *reinterpret_cast<const bf16x8*>(&val[(size_t)r * DMODEL + f]);
  f32x4 s0 = *reinterpret_cast<const f32x4*>(&S[b * DMODEL + f]);
  f32x4 s1 = *reinterpret_cast<const f32x4*>(&S[b * DMODEL + f + 4]);
  bf16x8 o;
#pragma unroll
  for (int j = 0; j < 4; j++) o[j] = (__bf16)((s0[j] + em1 * (float)v[j]) * inv);
#pragma unroll
  for (int j = 0; j < 4; j++) o[j + 4] = (__bf16)((s1[j] + em1 * (float)v[j + 4]) * inv);
  *reinterpret_cast<bf16x8*>(&u[(size_t)r * DMODEL + f]) = o;
}

// ---------------- C[m,n] = sum_k A[m,k] * B[n,k]  (both row-major, k contiguous) ----------------
// 128x128 tile, BK=64, 512 threads (8 waves, 2x4), double-buffered LDS, 2-phase pipeline,
// XOR-swizzled LDS (both-sides: pre-swizzled global source + swizzled ds_read).
__device__ __forceinline__ void store_val(float* p, float v) { *p = v; }
__device__ __forceinline__ void store_val(__hip_bfloat16* p, float v) { *p = __float2bfloat16(v); }

template <typename OutT>
__global__ __launch_bounds__(512) void gemm_bt(const __hip_bfloat16* __restrict__ A,
                                               const __hip_bfloat16* __restrict__ B,
                                               OutT* __restrict__ C, int M, int N, int K) {
  __shared__ __hip_bfloat16 As[2][128 * 64];
  __shared__ __hip_bfloat16 Bs[2][128 * 64];
  const int t = threadIdx.x;
  const int lane = t & 63;
  const int w = t >> 6;            // wave 0..7
  const int wm = w >> 2;           // 0..1 -> 64-row block
  const int wn = w & 3;            // 0..3 -> 32-col block
  const int tileM = blockIdx.y * 128, tileN = blockIdx.x * 128;

  const int fr = lane & 15;        // fragment row
  const int kg = lane >> 4;        // k-group (8 bf16 each)
  const int xsw = (fr & 7) << 4;   // read-side XOR swizzle (bytes, bits 4-6)

  f32x4 acc[4][2] = {};

  // staging: thread t covers row t>>3 (and +64), swizzled bf16 col
  const int srow = t >> 3;                          // 0..63
  const int scol = ((t & 7) ^ (srow & 7)) * 8;      // pre-swizzled source column
  const __hip_bfloat16* gA = A + (size_t)(tileM + srow) * K + scol;
  const __hip_bfloat16* gB = B + (size_t)(tileN + srow) * K + scol;

  const int nt = K >> 6;
  // prologue: stage tile 0 into buf 0
  gload_lds16(gA, &As[0][w * 512]);
  gload_lds16(gA + (size_t)64 * K, &As[0][4096 + w * 512]);
  gload_lds16(gB, &Bs[0][w * 512]);
  gload_lds16(gB + (size_t)64 * K, &Bs[0][4096 + w * 512]);
  __syncthreads();

  for (int kt = 0; kt < nt; kt++) {
    // issue next-tile stage first so it overlaps this tile's compute
    if (kt + 1 < nt) {
      int kb = (kt + 1) << 6;
      int nb = (kt + 1) & 1;
      gload_lds16(gA + kb, &As[nb][w * 512]);
      gload_lds16(gA + kb + (size_t)64 * K, &As[nb][4096 + w * 512]);
      gload_lds16(gB + kb, &Bs[nb][w * 512]);
      gload_lds16(gB + kb + (size_t)64 * K, &Bs[nb][4096 + w * 512]);
    }
    const char* aB = (const char*)&As[kt & 1][0];
    const char* bB = (const char*)&Bs[kt & 1][0];
#pragma unroll
    for (int kk = 0; kk < 2; kk++) {
      const int koff = (kk * 64 + kg * 16) ^ xsw;   // swizzled byte-in-row
      bf16x8 aF[4], bF[2];
#pragma unroll
      for (int i = 0; i < 4; i++)
        aF[i] = *reinterpret_cast<const bf16x8*>(aB + (wm * 64 + i * 16 + fr) * 128 + koff);
#pragma unroll
      for (int j = 0; j < 2; j++)
        bF[j] = *reinterpret_cast<const bf16x8*>(bB + (wn * 32 + j * 16 + fr) * 128 + koff);
#pragma unroll
      for (int i = 0; i < 4; i++)
#pragma unroll
        for (int j = 0; j < 2; j++)
          acc[i][j] = __builtin_amdgcn_mfma_f32_16x16x32_bf16(aF[i], bF[j], acc[i][j], 0, 0, 0);
    }
    __syncthreads();   // lgkm drain (reads of cur done) + vm drain (next tile landed)
  }

  const int cr = (lane >> 4) * 4;  // C row base within fragment
  const int cc = lane & 15;        // C col within fragment
#pragma unroll
  for (int i = 0; i < 4; i++)
#pragma unroll
    for (int j = 0; j < 2; j++)
#pragma unroll
      for (int r = 0; r < 4; r++) {
        int row = tileM + wm * 64 + i * 16 + cr + r;
        int col = tileN + wn * 32 + j * 16 + cc;
        store_val(&C[(size_t)row * N + col], acc[i][j][r]);
      }
}

extern "C" void kernel_launch(void* const* d_in, const int* in_sizes, int n_in,
                              void* d_out, int out_size, void* d_ws, size_t ws_size,
                              hipStream_t stream) {
  const float* x  = (const float*)d_in[0];
  const float* fl = (const float*)d_in[1];
  const float* fr = (const float*)d_in[2];
  const float* Wv = (const float*)d_in[3];
  const float* Wo = (const float*)d_in[4];
  float* out = (float*)d_out;

  char* ws = (char*)d_ws;
  __hip_bfloat16* xb   = (__hip_bfloat16*)(ws);                          // 8 MB (reused as ub)
  __hip_bfloat16* wvb  = (__hip_bfloat16*)(ws + ( 8u << 20));            // 2 MB
  __hip_bfloat16* wob  = (__hip_bfloat16*)(ws + (10u << 20));            // 2 MB
  __hip_bfloat16* valb = (__hip_bfloat16*)(ws + (12u << 20));            // 8 MB
  float* S  = (float*)(ws + (20u << 20));                                // 16 KB
  float* ed = (float*)(ws + (20u << 20) + (64u << 10));                  // 256 KB
  __hip_bfloat16* ub = xb;  // xb is dead after GEMM1; reuse for u

  cvt_kernel<<<6144, 256, 0, stream>>>(x, Wv, Wo, xb, wvb, wob);
  diag_kernel<<<4096, 256, 0, stream>>>(fl, fr, ed, S);
  gemm_bt<__hip_bfloat16><<<dim3(DMODEL / 128, MROWS / 128), 512, 0, stream>>>(
      xb, wvb, valb, MROWS, DMODEL, DMODEL);
  colsum_kernel<<<dim3(32, 4), 256, 0, stream>>>(valb, S);
  u_kernel<<<2048, 256, 0, stream>>>(valb, S, ed, ub);
  gemm_bt<float><<<dim3(DMODEL / 128, MROWS / 128), 512, 0, stream>>>(
      ub, wob, out, MROWS, DMODEL, DMODEL);
}

// Round 3
// 57.599 us; speedup vs baseline: 1.6376x; 1.2325x over previous
//
#include <hip/hip_runtime.h>
#include <hip/hip_bf16.h>

typedef __bf16 bf16x8 __attribute__((ext_vector_type(8)));
typedef __bf16 bf16x4 __attribute__((ext_vector_type(4)));
typedef float f32x4 __attribute__((ext_vector_type(4)));

#define DMODEL 1024
#define NBATCH 4
#define NHEAD 16
#define NSEQ 1024
#define MROWS (NBATCH * NSEQ)   // 4096

// async global->LDS, 16B per lane. LDS dest must be wave-uniform base; HW adds lane*16.
__device__ __forceinline__ void gload_lds16(const void* g, void* l) {
  __builtin_amdgcn_global_load_lds(
      (const __attribute__((address_space(1))) unsigned int*)g,
      (__attribute__((address_space(3))) unsigned int*)l, 16, 0, 0);
}

// ---------------- L1 prep: cvt x,Wo -> bf16; transpose-cvt Wv; diag -> {e-1, inv}; zero S ----
// grid: [0,5120) cvt, [5120,6144) Wv transpose tiles, [6144,10240) diag rows
__global__ void prep_kernel(const float* __restrict__ x, const float* __restrict__ wv,
                            const float* __restrict__ wo, const float* __restrict__ fl,
                            const float* __restrict__ fr, __hip_bfloat16* __restrict__ xb,
                            __hip_bfloat16* __restrict__ wob, __hip_bfloat16* __restrict__ wvtb,
                            float2* __restrict__ ed2, float* __restrict__ S) {
  __shared__ float ls[32][33];
  const int blk = blockIdx.x, tid = threadIdx.x;
  if (blk < 5120) {
    const int XQ = (MROWS * DMODEL) / 4;   // 1048576 float4s -> 4096 blocks
    int t = blk * 256 + tid;
    const float* src; __hip_bfloat16* dst; int i;
    if (t < XQ) { src = x; dst = xb; i = t; }
    else        { src = wo; dst = wob; i = t - XQ; }
    float4 v = reinterpret_cast<const float4*>(src)[i];
    bf16x4 o = { (__bf16)v.x, (__bf16)v.y, (__bf16)v.z, (__bf16)v.w };
    reinterpret_cast<bf16x4*>(dst)[i] = o;
  } else if (blk < 6144) {
    // wvtb[n][j] = Wv[j][n], bf16
    int tile = blk - 5120;
    int tr = tile >> 5, tc = tile & 31;     // 32x32 tiles
    int r = tid >> 3, c4 = (tid & 7) * 4;
    float4 v = *reinterpret_cast<const float4*>(&wv[(size_t)(tr * 32 + r) * DMODEL + tc * 32 + c4]);
    ls[r][c4] = v.x; ls[r][c4 + 1] = v.y; ls[r][c4 + 2] = v.z; ls[r][c4 + 3] = v.w;
    __syncthreads();
    bf16x4 o = { (__bf16)ls[c4][r], (__bf16)ls[c4 + 1][r],
                 (__bf16)ls[c4 + 2][r], (__bf16)ls[c4 + 3][r] };
    *reinterpret_cast<bf16x4*>(&wvtb[(size_t)(tc * 32 + r) * DMODEL + tr * 32 + c4]) = o;
  } else {
    int db = blk - 6144;
    if (db == 0) {
#pragma unroll
      for (int i = 0; i < (NBATCH * DMODEL) / 256; i++) S[i * 256 + tid] = 0.f;
    }
    int t = db * 256 + tid;                 // 16 threads per row
    int row = t >> 4, sub = t & 15;
    float4 a = reinterpret_cast<const float4*>(fl)[row * 16 + sub];
    float4 b = reinterpret_cast<const float4*>(fr)[row * 16 + sub];
    float s = a.x * b.x + a.y * b.y + a.z * b.z + a.w * b.w;
    s += __shfl_xor(s, 1);
    s += __shfl_xor(s, 2);
    s += __shfl_xor(s, 4);
    s += __shfl_xor(s, 8);
    if (sub == 0) {
      float e = expf(s);
      ed2[row] = make_float2(e - 1.f, 1.f / (e + (float)(NSEQ - 1)));
    }
  }
}

// ---------------- xsum[b,k] = sum_n x[b,n,k] (fp32, atomics into pre-zeroed S) ----------------
__global__ void xsum_kernel(const float* __restrict__ x, float* __restrict__ S) {
  // grid (128, 4): b = bx>>5, 32-row chunk = bx&31; col = by*256+tid
  int c = blockIdx.y * 256 + threadIdx.x;
  int b = blockIdx.x >> 5, ch = blockIdx.x & 31;
  const float* p = x + ((size_t)b * NSEQ + ch * 32) * DMODEL + c;
  float s = 0.f;
#pragma unroll 8
  for (int n = 0; n < 32; n++) s += p[(size_t)n * DMODEL];
  atomicAdd(&S[b * DMODEL + c], s);
}

// ---------------- Wc[c,k] = sum_j Wo[c,j]*Wvt[k,j] : 64x64 tile, BK=64, dbuf, swizzled -------
__global__ __launch_bounds__(256) void gemm64_bt(const __hip_bfloat16* __restrict__ A,
                                                 const __hip_bfloat16* __restrict__ B,
                                                 __hip_bfloat16* __restrict__ C,
                                                 int M, int N, int K) {
  __shared__ __hip_bfloat16 As[2][64 * 64];
  __shared__ __hip_bfloat16 Bs[2][64 * 64];
  const int t = threadIdx.x, lane = t & 63, w = t >> 6;   // 4 waves
  const int wm = w >> 1, wn = w & 1;                       // wave tile 32x32
  const int tileM = blockIdx.y * 64, tileN = blockIdx.x * 64;
  const int fr = lane & 15, kg = lane >> 4;
  const int xsw = (fr & 7) << 4;
  f32x4 acc[2][2] = {};

  const int srow = w * 8 + (lane >> 3);                    // 0..31
  const int scol = ((lane & 7) ^ (lane >> 3)) * 8;         // pre-swizzled source col
  const __hip_bfloat16* gA = A + (size_t)(tileM + srow) * K + scol;
  const __hip_bfloat16* gB = B + (size_t)(tileN + srow) * K + scol;

  const int nt = K >> 6;
  gload_lds16(gA, &As[0][w * 512]);
  gload_lds16(gA + 32 * (size_t)K, &As[0][2048 + w * 512]);
  gload_lds16(gB, &Bs[0][w * 512]);
  gload_lds16(gB + 32 * (size_t)K, &Bs[0][2048 + w * 512]);
  __syncthreads();

  for (int kt = 0; kt < nt; kt++) {
    if (kt + 1 < nt) {
      int kb = (kt + 1) << 6, nb = (kt + 1) & 1;
      gload_lds16(gA + kb, &As[nb][w * 512]);
      gload_lds16(gA + kb + 32 * (size_t)K, &As[nb][2048 + w * 512]);
      gload_lds16(gB + kb, &Bs[nb][w * 512]);
      gload_lds16(gB + kb + 32 * (size_t)K, &Bs[nb][2048 + w * 512]);
    }
    const char* aB = (const char*)&As[kt & 1][0];
    const char* bB = (const char*)&Bs[kt & 1][0];
#pragma unroll
    for (int kk = 0; kk < 2; kk++) {
      const int koff = (kk * 64 + kg * 16) ^ xsw;
      bf16x8 aF[2], bF[2];
#pragma unroll
      for (int i = 0; i < 2; i++)
        aF[i] = *reinterpret_cast<const bf16x8*>(aB + (wm * 32 + i * 16 + fr) * 128 + koff);
#pragma unroll
      for (int j = 0; j < 2; j++)
        bF[j] = *reinterpret_cast<const bf16x8*>(bB + (wn * 32 + j * 16 + fr) * 128 + koff);
#pragma unroll
      for (int i = 0; i < 2; i++)
#pragma unroll
        for (int j = 0; j < 2; j++)
          acc[i][j] = __builtin_amdgcn_mfma_f32_16x16x32_bf16(aF[i], bF[j], acc[i][j], 0, 0, 0);
    }
    __syncthreads();
  }

  const int cr = (lane >> 4) * 4, cc = lane & 15;
#pragma unroll
  for (int i = 0; i < 2; i++)
#pragma unroll
    for (int j = 0; j < 2; j++)
#pragma unroll
      for (int r = 0; r < 4; r++)
        C[(size_t)(tileM + wm * 32 + i * 16 + cr + r) * N + tileN + wn * 32 + j * 16 + cc] =
            __float2bfloat16(acc[i][j][r]);
}

// ---------------- T[b,c] = sum_k xsum[b,k] * Wc[c,k] (one wave per output) ----------------
__global__ void t_kernel(const float* __restrict__ S, const __hip_bfloat16* __restrict__ Wc,
                         float* __restrict__ T) {
  int g = blockIdx.x * 4 + (threadIdx.x >> 6);   // 0..4095
  int lane = threadIdx.x & 63;
  int b = g >> 10, c = g & 1023;
  const __hip_bfloat16* wp = Wc + (size_t)c * DMODEL + lane * 16;
  bf16x8 w0 = *reinterpret_cast<const bf16x8*>(wp);
  bf16x8 w1 = *reinterpret_cast<const bf16x8*>(wp + 8);
  const float* sp = S + b * DMODEL + lane * 16;
  float s = 0.f;
#pragma unroll
  for (int i = 0; i < 8; i++) s += sp[i] * (float)w0[i];
#pragma unroll
  for (int i = 0; i < 8; i++) s += sp[i + 8] * (float)w1[i];
#pragma unroll
  for (int d = 1; d < 64; d <<= 1) s += __shfl_xor(s, d);
  if (lane == 0) T[g] = s;
}

// ------- out[r,c] = inv * (T[b,c] + em1 * sum_k x[r,k]*Wc[c,k]) : 128x128, BK=64, dbuf -------
__global__ __launch_bounds__(512) void gemm128_epi(const __hip_bfloat16* __restrict__ A,
                                                   const __hip_bfloat16* __restrict__ B,
                                                   float* __restrict__ C, int M, int N, int K,
                                                   const float2* __restrict__ ed2,
                                                   const float* __restrict__ T) {
  __shared__ __hip_bfloat16 As[2][128 * 64];
  __shared__ __hip_bfloat16 Bs[2][128 * 64];
  const int t = threadIdx.x, lane = t & 63, w = t >> 6;   // 8 waves
  const int wm = w >> 2, wn = w & 3;                       // wave tile 64x32
  const int tileM = blockIdx.y * 128, tileN = blockIdx.x * 128;
  const int fr = lane & 15, kg = lane >> 4;
  const int xsw = (fr & 7) << 4;
  f32x4 acc[4][2] = {};

  const int srow = t >> 3;                          // 0..63
  const int scol = ((t & 7) ^ (srow & 7)) * 8;
  const __hip_bfloat16* gA = A + (size_t)(tileM + srow) * K + scol;
  const __hip_bfloat16* gB = B + (size_t)(tileN + srow) * K + scol;

  const int nt = K >> 6;
  gload_lds16(gA, &As[0][w * 512]);
  gload_lds16(gA + (size_t)64 * K, &As[0][4096 + w * 512]);
  gload_lds16(gB, &Bs[0][w * 512]);
  gload_lds16(gB + (size_t)64 * K, &Bs[0][4096 + w * 512]);
  __syncthreads();

  for (int kt = 0; kt < nt; kt++) {
    if (kt + 1 < nt) {
      int kb = (kt + 1) << 6, nb = (kt + 1) & 1;
      gload_lds16(gA + kb, &As[nb][w * 512]);
      gload_lds16(gA + kb + (size_t)64 * K, &As[nb][4096 + w * 512]);
      gload_lds16(gB + kb, &Bs[nb][w * 512]);
      gload_lds16(gB + kb + (size_t)64 * K, &Bs[nb][4096 + w * 512]);
    }
    const char* aB = (const char*)&As[kt & 1][0];
    const char* bB = (const char*)&Bs[kt & 1][0];
#pragma unroll
    for (int kk = 0; kk < 2; kk++) {
      const int koff = (kk * 64 + kg * 16) ^ xsw;
      bf16x8 aF[4], bF[2];
#pragma unroll
      for (int i = 0; i < 4; i++)
        aF[i] = *reinterpret_cast<const bf16x8*>(aB + (wm * 64 + i * 16 + fr) * 128 + koff);
#pragma unroll
      for (int j = 0; j < 2; j++)
        bF[j] = *reinterpret_cast<const bf16x8*>(bB + (wn * 32 + j * 16 + fr) * 128 + koff);
#pragma unroll
      for (int i = 0; i < 4; i++)
#pragma unroll
        for (int j = 0; j < 2; j++)
          acc[i][j] = __builtin_amdgcn_mfma_f32_16x16x32_bf16(aF[i], bF[j], acc[i][j], 0, 0, 0);
    }
    __syncthreads();
  }

  const int cr = (lane >> 4) * 4, cc = lane & 15;
  const int b = tileM >> 10;   // 128-row tile never crosses a batch boundary
#pragma unroll
  for (int i = 0; i < 4; i++)
#pragma unroll
    for (int j = 0; j < 2; j++) {
      int col = tileN + wn * 32 + j * 16 + cc;
      int hb = ((b << 4) + (col >> 6)) << 10;   // ed2 base for (b, head)
      float tv = T[(b << 10) + col];
#pragma unroll
      for (int r = 0; r < 4; r++) {
        int row = tileM + wm * 64 + i * 16 + cr + r;
        float2 ei = ed2[hb + (row & 1023)];     // {e-1, 1/(e+N-1)}
        C[(size_t)row * N + col] = ei.y * (tv + ei.x * acc[i][j][r]);
      }
    }
}

extern "C" void kernel_launch(void* const* d_in, const int* in_sizes, int n_in,
                              void* d_out, int out_size, void* d_ws, size_t ws_size,
                              hipStream_t stream) {
  const float* x  = (const float*)d_in[0];
  const float* fl = (const float*)d_in[1];
  const float* fr = (const float*)d_in[2];
  const float* Wv = (const float*)d_in[3];
  const float* Wo = (const float*)d_in[4];
  float* out = (float*)d_out;

  char* ws = (char*)d_ws;
  __hip_bfloat16* xb   = (__hip_bfloat16*)(ws);                    // 8 MB
  __hip_bfloat16* wob  = (__hip_bfloat16*)(ws + ( 8u << 20));      // 2 MB
  __hip_bfloat16* wvtb = (__hip_bfloat16*)(ws + (10u << 20));      // 2 MB  (Wv^T)
  __hip_bfloat16* wcb  = (__hip_bfloat16*)(ws + (12u << 20));      // 2 MB  (Wc = Wo*Wv)
  float*  S   = (float*) (ws + (14u << 20));                       // 16 KB (xsum)
  float*  T   = (float*) (ws + (14u << 20) + (64u << 10));         // 16 KB
  float2* ed2 = (float2*)(ws + (14u << 20) + (128u << 10));        // 512 KB

  prep_kernel<<<10240, 256, 0, stream>>>(x, Wv, Wo, fl, fr, xb, wob, wvtb, ed2, S);
  xsum_kernel<<<dim3(128, 4), 256, 0, stream>>>(x, S);
  gemm64_bt<<<dim3(16, 16), 256, 0, stream>>>(wob, wvtb, wcb, DMODEL, DMODEL, DMODEL);
  t_kernel<<<1024, 256, 0, stream>>>(S, wcb, T);
  gemm128_epi<<<dim3(DMODEL / 128, MROWS / 128), 512, 0, stream>>>(
      xb, wcb, out, MROWS, DMODEL, DMODEL, ed2, T);
}